// Round 2
// baseline (86.918 us; speedup 1.0000x reference)
//
#include <hip/hip_runtime.h>

#define NSEG 196
#define BATCH 8
#define IMH 224
#define IMW 224
#define NPIX (IMH * IMW)       // 50176
#define EMB 768
#define ST 6                   // c0,c1,c2,x,y,count
#define SEGSZ (NSEG * ST)      // 1176
#define NCOPY 8                // LDS accumulator replication (per tid&7)
#define CHUNK 512              // pixels per block
#define CPB (NPIX / CHUNK)     // 98 chunks per batch image
#define NBLK1 (BATCH * CPB)    // 784 blocks

// ---------------------------------------------------------------------------
// Kernel 1: per-chunk partial sums [c0,c1,c2,x,y,cnt] per segment.
// 8-way replicated LDS accumulators to cut same-address atomic serialization.
// Each block writes its private 1176-float slab to ws — NO global atomics.
// ---------------------------------------------------------------------------
__global__ __launch_bounds__(256)
void spt_accum(const float* __restrict__ img, const int* __restrict__ seg,
               float* __restrict__ ws) {
    __shared__ float lacc[NCOPY][SEGSZ];
    const int tid = threadIdx.x;
    for (int i = tid; i < NCOPY * SEGSZ; i += 256) (&lacc[0][0])[i] = 0.0f;
    __syncthreads();

    const int batch = blockIdx.x / CPB;
    const int chunk = blockIdx.x % CPB;
    const int n = chunk * CHUNK + tid * 2;      // 2 consecutive pixels/thread

    const float* imgb = img + (size_t)batch * 3 * NPIX;
    const float2 c0 = *(const float2*)(imgb + n);
    const float2 c1 = *(const float2*)(imgb + NPIX + n);
    const float2 c2 = *(const float2*)(imgb + 2 * NPIX + n);
    const int2   s2 = *(const int2*)(seg + (size_t)batch * NPIX + n);

    // 224 is even and n is even -> the pixel pair never crosses a row.
    const int h  = n / IMW;
    const int wb = n - h * IMW;
    const float y = (float)h * (1.0f / 223.0f);
    float* lc = &lacc[tid & (NCOPY - 1)][0];

    {
        float* p = lc + s2.x * ST;
        atomicAdd(p + 0, c0.x);
        atomicAdd(p + 1, c1.x);
        atomicAdd(p + 2, c2.x);
        atomicAdd(p + 3, (float)wb * (1.0f / 223.0f));
        atomicAdd(p + 4, y);
        atomicAdd(p + 5, 1.0f);
    }
    {
        float* p = lc + s2.y * ST;
        atomicAdd(p + 0, c0.y);
        atomicAdd(p + 1, c1.y);
        atomicAdd(p + 2, c2.y);
        atomicAdd(p + 3, (float)(wb + 1) * (1.0f / 223.0f));
        atomicAdd(p + 4, y);
        atomicAdd(p + 5, 1.0f);
    }
    __syncthreads();

    // Merge the 8 copies and store this block's private partial slab.
    float* wsb = ws + (size_t)blockIdx.x * SEGSZ;
    for (int i = tid; i < SEGSZ; i += 256) {
        float v = lacc[0][i];
        #pragma unroll
        for (int c = 1; c < NCOPY; ++c) v += lacc[c][i];
        wsb[i] = v;
    }
}

// ---------------------------------------------------------------------------
// Kernel 2: reduce the 98 chunk-partials for (batch,seg), then project:
// out[bs][e] = (sum_f fs[f]*W[f][e] + cnt*bias[e]) / max(cnt,1)
// Grid: B*NSEG = 1568 blocks, 256 threads. Wave 0 does the reduction.
// ---------------------------------------------------------------------------
__global__ __launch_bounds__(256)
void spt_proj(const float* __restrict__ ws, const float* __restrict__ Wm,
              const float* __restrict__ bias, float* __restrict__ out) {
    const int bs = blockIdx.x;
    const int batch = bs / NSEG;
    const int s = bs - batch * NSEG;
    __shared__ float fs[ST];
    const int tid = threadIdx.x;

    if (tid < 64) {
        float v0 = 0, v1 = 0, v2 = 0, v3 = 0, v4 = 0, v5 = 0;
        const float* base = ws + (size_t)batch * CPB * SEGSZ + s * ST;
        for (int c = tid; c < CPB; c += 64) {
            const float* p = base + (size_t)c * SEGSZ;
            v0 += p[0]; v1 += p[1]; v2 += p[2];
            v3 += p[3]; v4 += p[4]; v5 += p[5];
        }
        #pragma unroll
        for (int off = 32; off > 0; off >>= 1) {
            v0 += __shfl_xor(v0, off, 64);
            v1 += __shfl_xor(v1, off, 64);
            v2 += __shfl_xor(v2, off, 64);
            v3 += __shfl_xor(v3, off, 64);
            v4 += __shfl_xor(v4, off, 64);
            v5 += __shfl_xor(v5, off, 64);
        }
        if (tid == 0) {
            fs[0] = v0; fs[1] = v1; fs[2] = v2;
            fs[3] = v3; fs[4] = v4; fs[5] = v5;
        }
    }
    __syncthreads();

    const float cnt = fs[5];
    const float inv = 1.0f / fmaxf(cnt, 1.0f);
    const float f0 = fs[0], f1 = fs[1], f2 = fs[2], f3 = fs[3], f4 = fs[4];

    float* outb = out + (size_t)bs * EMB;
    #pragma unroll
    for (int it = 0; it < 3; ++it) {
        const int e = tid + it * 256;
        float acc = cnt * bias[e];
        acc = fmaf(f0, Wm[0 * EMB + e], acc);
        acc = fmaf(f1, Wm[1 * EMB + e], acc);
        acc = fmaf(f2, Wm[2 * EMB + e], acc);
        acc = fmaf(f3, Wm[3 * EMB + e], acc);
        acc = fmaf(f4, Wm[4 * EMB + e], acc);
        outb[e] = acc * inv;
    }
}

extern "C" void kernel_launch(void* const* d_in, const int* in_sizes, int n_in,
                              void* d_out, int out_size, void* d_ws, size_t ws_size,
                              hipStream_t stream) {
    const float* img  = (const float*)d_in[0];   // [8,3,224,224]
    const int*   seg  = (const int*)d_in[1];     // [8,224,224]
    const float* Wm   = (const float*)d_in[2];   // [5,768]
    const float* bias = (const float*)d_in[3];   // [768]
    float* out = (float*)d_out;                  // [8,196,768]
    float* ws  = (float*)d_ws;                   // [784][1176] partial slabs

    // Every slot of ws is written by spt_accum before spt_proj reads it —
    // no memset needed despite the 0xAA poison.
    spt_accum<<<NBLK1, 256, 0, stream>>>(img, seg, ws);
    spt_proj<<<BATCH * NSEG, 256, 0, stream>>>(ws, Wm, bias, out);
}

// Round 3
// 82.200 us; speedup vs baseline: 1.0574x; 1.0574x over previous
//
#include <hip/hip_runtime.h>

#define NSEG 196
#define BATCH 8
#define IMH 224
#define IMW 224
#define NPIX (IMH * IMW)       // 50176
#define EMB 768
#define ST 6                   // c0,c1,c2,x,y,count
#define SEGSZ (NSEG * ST)      // 1176
#define NCOPY 4                // LDS accumulator replication (tid&3)
#define PXT 4                  // pixels per thread (float4)
#define CHUNK (256 * PXT)      // 1024 pixels per block
#define CPB (NPIX / CHUNK)     // 49 chunks per batch image (exact)
#define NBLK1 (BATCH * CPB)    // 392 blocks

// ---------------------------------------------------------------------------
// Kernel 1: per-chunk partial sums [c0,c1,c2,x,y,cnt] per segment.
// float4 pixel loads, 4-way replicated LDS accumulators, private slab store.
// LDS = 18816 B -> 8 blocks/CU -> full 32-wave occupancy.
// ---------------------------------------------------------------------------
__global__ __launch_bounds__(256)
void spt_accum(const float* __restrict__ img, const int* __restrict__ seg,
               float* __restrict__ ws) {
    __shared__ float lacc[NCOPY][SEGSZ];
    const int tid = threadIdx.x;
    for (int i = tid; i < NCOPY * SEGSZ; i += 256) (&lacc[0][0])[i] = 0.0f;
    __syncthreads();

    const int batch = blockIdx.x / CPB;
    const int chunk = blockIdx.x % CPB;
    const int n = chunk * CHUNK + tid * PXT;   // 4 consecutive pixels

    const float* imgb = img + (size_t)batch * 3 * NPIX;
    const float4 c0 = *(const float4*)(imgb + n);
    const float4 c1 = *(const float4*)(imgb + NPIX + n);
    const float4 c2 = *(const float4*)(imgb + 2 * NPIX + n);
    const int4   s4 = *(const int4*)(seg + (size_t)batch * NPIX + n);

    // n%4==0 and 224%4==0 -> the 4-pixel group never crosses a row.
    const int h  = n / IMW;
    const int w0 = n - h * IMW;
    const float y = (float)h * (1.0f / 223.0f);
    float* lc = lacc[tid & (NCOPY - 1)];

    const float cc0[4] = {c0.x, c0.y, c0.z, c0.w};
    const float cc1[4] = {c1.x, c1.y, c1.z, c1.w};
    const float cc2[4] = {c2.x, c2.y, c2.z, c2.w};
    const int   ss[4]  = {s4.x, s4.y, s4.z, s4.w};

    #pragma unroll
    for (int k = 0; k < 4; ++k) {
        float* p = lc + ss[k] * ST;
        atomicAdd(p + 0, cc0[k]);
        atomicAdd(p + 1, cc1[k]);
        atomicAdd(p + 2, cc2[k]);
        atomicAdd(p + 3, (float)(w0 + k) * (1.0f / 223.0f));
        atomicAdd(p + 4, y);
        atomicAdd(p + 5, 1.0f);
    }
    __syncthreads();

    // Merge the 4 copies; store this block's private partial slab.
    float* wsb = ws + (size_t)blockIdx.x * SEGSZ;
    for (int i = tid; i < SEGSZ; i += 256) {
        wsb[i] = lacc[0][i] + lacc[1][i] + lacc[2][i] + lacc[3][i];
    }
}

// ---------------------------------------------------------------------------
// Kernel 2: reduce 49 chunk-partials for (batch,seg), then project:
// out[bs][e] = (sum_f fs[f]*W[f][e] + cnt*bias[e]) / max(cnt,1)
// W/bias loads hoisted before the barrier to overlap the reduction latency.
// ---------------------------------------------------------------------------
__global__ __launch_bounds__(256)
void spt_proj(const float* __restrict__ ws, const float* __restrict__ Wm,
              const float* __restrict__ bias, float* __restrict__ out) {
    const int bs = blockIdx.x;
    const int batch = bs / NSEG;
    const int s = bs - batch * NSEG;
    const int tid = threadIdx.x;
    __shared__ float fs[ST];

    // Hoisted weight/bias loads (independent of the reduction below).
    float w0[3], w1[3], w2[3], w3[3], w4[3], bb[3];
    #pragma unroll
    for (int it = 0; it < 3; ++it) {
        const int e = tid + it * 256;
        w0[it] = Wm[0 * EMB + e];
        w1[it] = Wm[1 * EMB + e];
        w2[it] = Wm[2 * EMB + e];
        w3[it] = Wm[3 * EMB + e];
        w4[it] = Wm[4 * EMB + e];
        bb[it] = bias[e];
    }

    if (tid < 64) {
        float v0 = 0, v1 = 0, v2 = 0, v3 = 0, v4 = 0, v5 = 0;
        if (tid < CPB) {
            const float* p = ws + ((size_t)batch * CPB + tid) * SEGSZ + s * ST;
            const float2 a = *(const float2*)(p + 0);
            const float2 b2 = *(const float2*)(p + 2);
            const float2 c = *(const float2*)(p + 4);
            v0 = a.x;  v1 = a.y;  v2 = b2.x;
            v3 = b2.y; v4 = c.x;  v5 = c.y;
        }
        #pragma unroll
        for (int off = 32; off > 0; off >>= 1) {
            v0 += __shfl_xor(v0, off, 64);
            v1 += __shfl_xor(v1, off, 64);
            v2 += __shfl_xor(v2, off, 64);
            v3 += __shfl_xor(v3, off, 64);
            v4 += __shfl_xor(v4, off, 64);
            v5 += __shfl_xor(v5, off, 64);
        }
        if (tid == 0) {
            fs[0] = v0; fs[1] = v1; fs[2] = v2;
            fs[3] = v3; fs[4] = v4; fs[5] = v5;
        }
    }
    __syncthreads();

    const float cnt = fs[5];
    const float inv = 1.0f / fmaxf(cnt, 1.0f);
    const float f0 = fs[0], f1 = fs[1], f2 = fs[2], f3 = fs[3], f4 = fs[4];

    float* outb = out + (size_t)bs * EMB;
    #pragma unroll
    for (int it = 0; it < 3; ++it) {
        const int e = tid + it * 256;
        float acc = cnt * bb[it];
        acc = fmaf(f0, w0[it], acc);
        acc = fmaf(f1, w1[it], acc);
        acc = fmaf(f2, w2[it], acc);
        acc = fmaf(f3, w3[it], acc);
        acc = fmaf(f4, w4[it], acc);
        outb[e] = acc * inv;
    }
}

extern "C" void kernel_launch(void* const* d_in, const int* in_sizes, int n_in,
                              void* d_out, int out_size, void* d_ws, size_t ws_size,
                              hipStream_t stream) {
    const float* img  = (const float*)d_in[0];   // [8,3,224,224]
    const int*   seg  = (const int*)d_in[1];     // [8,224,224]
    const float* Wm   = (const float*)d_in[2];   // [5,768]
    const float* bias = (const float*)d_in[3];   // [768]
    float* out = (float*)d_out;                  // [8,196,768]
    float* ws  = (float*)d_ws;                   // [392][1176] partial slabs

    // Every used slot of ws is written by spt_accum before spt_proj reads it.
    spt_accum<<<NBLK1, 256, 0, stream>>>(img, seg, ws);
    spt_proj<<<BATCH * NSEG, 256, 0, stream>>>(ws, Wm, bias, out);
}